// Round 5
// baseline (146.705 us; speedup 1.0000x reference)
//
#include <hip/hip_runtime.h>
#include <stdint.h>

#define B_    8
#define N_    512
#define DIN   1024
#define DOUT  1024
#define L_    16
#define T_    4096

#define BM 256
#define BN 256
#define BK 64
#define NB (DOUT / BN)          /* 4 */
#define NKT (DIN / BK)          /* 16 K-tiles */
#define NIT (NKT / 2)           /* 8 iterations, 2 K-tiles each */
#define MT_MAX 144
#define ZROW ((long)B_ * N_)    /* zero-row index in pooled_bf16 */

typedef __attribute__((ext_vector_type(8))) short short8;
typedef __attribute__((ext_vector_type(4))) float f32x4;

#define POOLED_ELEMS ((long)B_ * N_ * DIN + DIN)
#define WS_W_OFF     ((size_t)POOLED_ELEMS * 2)
#define WS_META_OFF  (WS_W_OFF + (size_t)L_ * DOUT * DIN * 2)

__device__ __forceinline__ unsigned short f2bf(float f) {
  unsigned u = __float_as_uint(f);
  u += 0x7FFFu + ((u >> 16) & 1u);   /* RNE */
  return (unsigned short)(u >> 16);
}

__device__ __forceinline__ void gload_lds16(const void* g, void* l) {
  __builtin_amdgcn_global_load_lds(
      (const __attribute__((address_space(1))) void*)g,
      (__attribute__((address_space(3))) void*)l, 16, 0, 0);
}

__device__ __forceinline__ void bar() {
  asm volatile("" ::: "memory");
  __builtin_amdgcn_s_barrier();
  asm volatile("" ::: "memory");
}

/* ---------------- kernel 1: fp32 -> bf16 conversion ---------------- */
__global__ void k_convert(const float* __restrict__ pooled,
                          const float* __restrict__ W,
                          unsigned short* __restrict__ wsP,
                          unsigned short* __restrict__ wsW) {
  const long np4 = (long)B_ * N_ * DIN / 4;
  const long nw4 = (long)L_ * DOUT * DIN / 4;
  const long nz4 = DIN / 4;
  long i = (long)blockIdx.x * blockDim.x + threadIdx.x;
  const long stride = (long)gridDim.x * blockDim.x;
  for (; i < np4 + nw4 + nz4; i += stride) {
    if (i < np4) {
      float4 v = ((const float4*)pooled)[i];
      ushort4 o = { f2bf(v.x), f2bf(v.y), f2bf(v.z), f2bf(v.w) };
      ((ushort4*)wsP)[i] = o;
    } else if (i < np4 + nw4) {
      float4 v = ((const float4*)W)[i - np4];
      ushort4 o = { f2bf(v.x), f2bf(v.y), f2bf(v.z), f2bf(v.w) };
      ((ushort4*)wsW)[i - np4] = o;
    } else {
      ushort4 z = {0, 0, 0, 0};
      ((ushort4*)wsP)[i - nw4] = z;
    }
  }
}

/* ---------------- kernel 2: map + group + tile table (fused) ---------------- */
__global__ void k_prep(const int* __restrict__ pidx,
                       unsigned* __restrict__ tlist,
                       int* __restrict__ goff, int* __restrict__ grows,
                       unsigned* __restrict__ table, int* __restrict__ ntiles) {
  __shared__ int sp[N_];
  __shared__ unsigned smap[T_];
  __shared__ int cnt[L_], pos[L_];
  const int tid = threadIdx.x;
  for (int i = tid; i < N_; i += 256) sp[i] = pidx[i];
  if (tid < L_) cnt[tid] = 0;
  __syncthreads();
  for (int t = tid; t < T_; t += 256) {
    int lo = 0, hi = N_;
    while (lo < hi) { int mid = (lo + hi) >> 1; if (sp[mid] < t) lo = mid + 1; else hi = mid; }
    int n, l;
    if (lo < N_) {
      int start = lo ? sp[lo - 1] + 1 : 0;
      int li = t - start;
      l = li > (L_ - 1) ? (L_ - 1) : li;
      n = lo;
    } else { n = 0xFFFF; l = L_ - 1; }
    smap[t] = (unsigned)n | ((unsigned)l << 16);
    atomicAdd(&cnt[l], 1);
  }
  __syncthreads();
  if (tid == 0) {
    int off = 0;
    for (int l = 0; l < L_; ++l) {
      pos[l] = off; goff[l] = off; grows[l] = cnt[l] * B_;
      off += cnt[l];
    }
  }
  __syncthreads();
  for (int t = tid; t < T_; t += 256) {
    unsigned m = smap[t];
    int l = m >> 16;
    int p = atomicAdd(&pos[l], 1);
    tlist[p] = (unsigned)t | ((m & 0xFFFFu) << 16);
  }
  __syncthreads();
  if (tid == 0) {
    int tt = 0;
    for (int l = 0; l < L_; ++l) {
      int rows = cnt[l] * B_;
      for (int r0 = 0; r0 < rows; r0 += BM) table[tt++] = (unsigned)l | ((unsigned)r0 << 4);
    }
    *ntiles = tt;
  }
}

/* ---------------- kernel 3: grouped gather-GEMM, deep 8-phase ----------
   256x256, BK=64, 8 waves (2M x 4N), wave tile 128x64.
   Double-buffered LDS (128 KiB): even tiles buf0, odd buf1 (static).
   Phases (per 2 K-tiles): balanced reads 8/8/4/4; staging slots give every
   half-tile a 3-6 phase lead; vmcnt(4) at p4/p8 only.                       */
__global__ __launch_bounds__(512, 1)
void k_gemm(const unsigned short* __restrict__ wsP,
            const unsigned short* __restrict__ wsW,
            const unsigned* __restrict__ tlist,
            const int* __restrict__ goff,
            const int* __restrict__ grows,
            const unsigned* __restrict__ table,
            const int* __restrict__ ntiles,
            float* __restrict__ out) {
  const int bid = blockIdx.x;
  const int mt = bid >> 2;
  const int nt = bid & 3;
  if (mt >= *ntiles) return;

  const unsigned te = table[mt];
  const int l    = te & 15;
  const int row0 = (int)(te >> 4);
  const int toff = goff[l];
  const int rows = grows[l];

  __shared__ __align__(16) unsigned short As[2][BM * BK];  /* 2 x 32 KiB */
  __shared__ __align__(16) unsigned short Bs[2][BN * BK];  /* 2 x 32 KiB */

  const int tid  = threadIdx.x;
  const int lane = tid & 63;
  const int w    = tid >> 6;      /* 0..7 */
  const int wm   = w >> 2;        /* 0..1 : 128-row half */
  const int wn   = w & 3;         /* 0..3 : 64-col quarter */

  /* ---- staging source pointers (inverse-swizzled 16B slot on SOURCE) ---- */
  const int srow = tid >> 3;                       /* 0..63 */
  const int sxor = ((tid & 7) ^ (srow & 7)) * 16;
  const char* aptr[4];
  const char* bptr[4];
#pragma unroll
  for (int h = 0; h < 2; ++h)
#pragma unroll
    for (int r = 0; r < 2; ++r) {
      int rt = h * 128 + r * 64 + srow;
      int rg = row0 + rt;
      long rowElem;
      if (rg < rows) {
        unsigned e = tlist[toff + (rg >> 3)];
        unsigned n = e >> 16;
        int b = rg & 7;
        rowElem = (n == 0xFFFFu) ? ZROW * (long)DIN
                                 : ((long)(b * N_ + (int)n)) * DIN;
      } else rowElem = ZROW * (long)DIN;
      aptr[h * 2 + r] = (const char*)(wsP + rowElem) + sxor;
      bptr[h * 2 + r] = (const char*)(wsW + ((long)l * DOUT + nt * BN + rt) * DIN) + sxor;
    }

/* stage one half-tile (128 rows x 64 k): 2 gload_lds per thread; linear dest */
#define STG_A(h, kt, bb) do { \
  gload_lds16(aptr[(h)*2+0] + (kt)*128, (char*)As[bb] + (((h)*128 + w*8)*128)); \
  gload_lds16(aptr[(h)*2+1] + (kt)*128, (char*)As[bb] + (((h)*128 + 64 + w*8)*128)); } while (0)
#define STG_B(h, kt, bb) do { \
  gload_lds16(bptr[(h)*2+0] + (kt)*128, (char*)Bs[bb] + (((h)*128 + w*8)*128)); \
  gload_lds16(bptr[(h)*2+1] + (kt)*128, (char*)Bs[bb] + (((h)*128 + 64 + w*8)*128)); } while (0)

  /* ---- fragment read offsets (same XOR on read side; refchecked R3) ---- */
  const int aoff = (wm * 128 + (lane & 15)) * 128;   /* bytes */
  const int boff = (wn * 64  + (lane & 15)) * 128;
  const int ax0  = (((lane >> 4)    ) ^ (lane & 7)) * 16;
  const int ax1  = (((lane >> 4) + 4) ^ (lane & 7)) * 16;

/* read af[0..3][kh] = m-frags (mb..mb+3) of buffer bb, k-half kh */
#define AF4(bb, mb, kh, AX) do { _Pragma("unroll") \
  for (int m_ = 0; m_ < 4; ++m_) \
    af[m_][kh] = *(const short8*)((const char*)As[bb] + aoff + ((mb)+m_)*2048 + (AX)); } while (0)
#define BF4(bb, kh, AX) do { _Pragma("unroll") \
  for (int n_ = 0; n_ < 4; ++n_) \
    bf[n_][kh] = *(const short8*)((const char*)Bs[bb] + boff + n_*2048 + (AX)); } while (0)
/* 16 MFMA: acc[mb..mb+3][0..3] += af[*][kh] x bf[*][kh] */
#define MM(mb, kh) do { _Pragma("unroll") \
  for (int n_ = 0; n_ < 4; ++n_) { _Pragma("unroll") \
    for (int m_ = 0; m_ < 4; ++m_) \
      acc[(mb)+m_][n_] = __builtin_amdgcn_mfma_f32_16x16x32_bf16(af[m_][kh], bf[n_][kh], acc[(mb)+m_][n_], 0, 0, 0); } } while (0)
#define LGKM0 asm volatile("s_waitcnt lgkmcnt(0)" ::: "memory")
#define P1 __builtin_amdgcn_s_setprio(1)
#define P0 __builtin_amdgcn_s_setprio(0)
#define VMC4 asm volatile("s_waitcnt vmcnt(4)" ::: "memory")
#define VMC0 asm volatile("s_waitcnt vmcnt(0)" ::: "memory")

  f32x4 acc[8][4];
#pragma unroll
  for (int m = 0; m < 8; ++m)
#pragma unroll
    for (int n = 0; n < 4; ++n)
      acc[m][n] = (f32x4){0.f, 0.f, 0.f, 0.f};

  short8 af[4][2], bf[4][2];

  /* ---- prologue: tile0 (4 halves -> buf0) + B(1) -> buf1; A(1) flows in-loop */
  STG_A(0, 0, 0); STG_A(1, 0, 0); STG_B(0, 0, 0); STG_B(1, 0, 0);
  STG_B(0, 1, 1); STG_B(1, 1, 1);
  VMC4;                                   /* 12 issued; oldest 8 = tile0 done */
  bar();

  for (int j = 0; j < NIT; ++j) {
    const int t1 = 2 * j + 1, t2 = 2 * j + 2, t3 = 2 * j + 3;
    const bool last = (j == NIT - 1);

    /* ---- tile t (buf0) ---- */
    /* p1: af[m0-3]k0 + bf k0; stage A.h0(t+1)->buf1 [lead 4] */
    AF4(0, 0, 0, ax0); BF4(0, 0, ax0);
    STG_A(0, t1, 1);
    bar(); LGKM0; P1; MM(0, 0); P0; bar();

    /* p2: af[m0-3]k1 + bf k1; stage A.h1(t+1)->buf1 [lead 3] */
    AF4(0, 0, 1, ax1); BF4(0, 1, ax1);
    STG_A(1, t1, 1);
    bar(); LGKM0; P1; MM(0, 1); P0; bar();

    /* p3: af[m4-7]k0; stage B.h0(t+2)->buf0 [lead 6] */
    AF4(0, 4, 0, ax0);
    if (t2 < NKT) STG_B(0, t2, 0);
    bar(); LGKM0; P1; MM(4, 0); P0; bar();

    /* p4: af[m4-7]k1; stage B.h1(t+2)->buf0 [lead 5]; gate A(t+1)+B(t+1) */
    AF4(0, 4, 1, ax1);
    if (t2 < NKT) STG_B(1, t2, 0);
    bar(); LGKM0; P1; MM(4, 1); P0;
    if (last) VMC0; else VMC4;
    bar();

    /* ---- tile t+1 (buf1) ---- */
    /* p5: af k0 + bf k0; stage A.h0(t+2)->buf0 [lead 4] */
    AF4(1, 0, 0, ax0); BF4(1, 0, ax0);
    if (t2 < NKT) STG_A(0, t2, 0);
    bar(); LGKM0; P1; MM(0, 0); P0; bar();

    /* p6: af k1 + bf k1; stage A.h1(t+2)->buf0 [lead 3] */
    AF4(1, 0, 1, ax1); BF4(1, 1, ax1);
    if (t2 < NKT) STG_A(1, t2, 0);
    bar(); LGKM0; P1; MM(0, 1); P0; bar();

    /* p7: af[m4-7]k0; stage B.h0(t+3)->buf1 [lead 6] */
    AF4(1, 4, 0, ax0);
    if (t3 < NKT) STG_B(0, t3, 1);
    bar(); LGKM0; P1; MM(4, 0); P0; bar();

    /* p8: af[m4-7]k1; stage B.h1(t+3)->buf1 [lead 5]; gate B(t+2)+A(t+2) */
    AF4(1, 4, 1, ax1);
    if (t3 < NKT) STG_B(1, t3, 1);
    bar(); LGKM0; P1; MM(4, 1); P0;
    if (last) VMC0; else VMC4;
    bar();
  }

  /* ---- epilogue: C/D layout col=lane&15, row=(lane>>4)*4+j ---- */
#pragma unroll
  for (int m = 0; m < 8; ++m) {
#pragma unroll
    for (int jj = 0; jj < 4; ++jj) {
      int rt = wm * 128 + m * 16 + (lane >> 4) * 4 + jj;
      int rg = row0 + rt;
      if (rg >= rows) continue;
      unsigned e = tlist[toff + (rg >> 3)];
      int b = rg & 7;
      int tt = (int)(e & 0xFFFFu);
      float* orow = out + ((long)b * T_ + tt) * DOUT + nt * BN + wn * 64 + (lane & 15);
#pragma unroll
      for (int n = 0; n < 4; ++n)
        orow[n * 16] = acc[m][n][jj];
    }
  }
#undef STG_A
#undef STG_B
#undef AF4
#undef BF4
#undef MM
#undef LGKM0
#undef P1
#undef P0
#undef VMC4
#undef VMC0
}

/* ---------------- launch ---------------- */
extern "C" void kernel_launch(void* const* d_in, const int* in_sizes, int n_in,
                              void* d_out, int out_size, void* d_ws, size_t ws_size,
                              hipStream_t stream) {
  const float* pooled = (const float*)d_in[0];
  const float* W      = (const float*)d_in[1];
  const int*   pidx   = (const int*)d_in[2];
  float* out = (float*)d_out;

  char* ws = (char*)d_ws;
  unsigned short* wsP = (unsigned short*)(ws);
  unsigned short* wsW = (unsigned short*)(ws + WS_W_OFF);
  int* meta  = (int*)(ws + WS_META_OFF);
  unsigned* tlist = (unsigned*)meta;
  int* goff  = meta + T_;
  int* grows = meta + T_ + 16;
  unsigned* table = (unsigned*)(meta + T_ + 32);
  int* ntiles = meta + T_ + 32 + MT_MAX;

  k_prep<<<1, 256, 0, stream>>>(pidx, tlist, goff, grows, table, ntiles);
  k_convert<<<2048, 256, 0, stream>>>(pooled, W, wsP, wsW);
  k_gemm<<<MT_MAX * NB, 512, 0, stream>>>(wsP, wsW, tlist, goff, grows, table,
                                          ntiles, out);
}

// Round 6
// 137.830 us; speedup vs baseline: 1.0644x; 1.0644x over previous
//
#include <hip/hip_runtime.h>
#include <stdint.h>

#define B_    8
#define N_    512
#define DIN   1024
#define DOUT  1024
#define L_    16
#define T_    4096

#define BM 256
#define BN 128
#define BK 32
#define NB (DOUT / BN)          /* 8 */
#define NKT (DIN / BK)          /* 32 K-tiles */
#define MT_MAX 160
#define ZROW ((long)B_ * N_)    /* zero-row index in pooled_bf16 */

typedef __attribute__((ext_vector_type(8))) short short8;
typedef __attribute__((ext_vector_type(4))) float f32x4;

#define POOLED_ELEMS ((long)B_ * N_ * DIN + DIN)
#define WS_W_OFF     ((size_t)POOLED_ELEMS * 2)
#define WS_META_OFF  (WS_W_OFF + (size_t)L_ * DOUT * DIN * 2)

__device__ __forceinline__ unsigned short f2bf(float f) {
  unsigned u = __float_as_uint(f);
  u += 0x7FFFu + ((u >> 16) & 1u);   /* RNE */
  return (unsigned short)(u >> 16);
}

__device__ __forceinline__ void gload_lds16(const void* g, void* l) {
  __builtin_amdgcn_global_load_lds(
      (const __attribute__((address_space(1))) void*)g,
      (__attribute__((address_space(3))) void*)l, 16, 0, 0);
}

__device__ __forceinline__ void bar() {
  asm volatile("" ::: "memory");
  __builtin_amdgcn_s_barrier();
  asm volatile("" ::: "memory");
}

/* ---------------- kernel 1: fp32 -> bf16 conversion ---------------- */
__global__ void k_convert(const float* __restrict__ pooled,
                          const float* __restrict__ W,
                          unsigned short* __restrict__ wsP,
                          unsigned short* __restrict__ wsW) {
  const long np4 = (long)B_ * N_ * DIN / 4;
  const long nw4 = (long)L_ * DOUT * DIN / 4;
  const long nz4 = DIN / 4;
  long i = (long)blockIdx.x * blockDim.x + threadIdx.x;
  const long stride = (long)gridDim.x * blockDim.x;
  for (; i < np4 + nw4 + nz4; i += stride) {
    if (i < np4) {
      float4 v = ((const float4*)pooled)[i];
      ushort4 o = { f2bf(v.x), f2bf(v.y), f2bf(v.z), f2bf(v.w) };
      ((ushort4*)wsP)[i] = o;
    } else if (i < np4 + nw4) {
      float4 v = ((const float4*)W)[i - np4];
      ushort4 o = { f2bf(v.x), f2bf(v.y), f2bf(v.z), f2bf(v.w) };
      ((ushort4*)wsW)[i - np4] = o;
    } else {
      ushort4 z = {0, 0, 0, 0};
      ((ushort4*)wsP)[i - nw4] = z;
    }
  }
}

/* ---------------- kernel 2: dedup prep ----------------
   Entry = t(12) | n(10) | rep(8).  Per segment n: positions 0..14 are
   unique rows (rep=1, group l=pos); positions >=15 all produce the SAME
   output row -> one entry in group 15 with rep=len-15 (split at 255).
   Invalid t's (beyond last index) -> zero-row entries (n=1023) in group 15. */
__global__ void k_prep(const int* __restrict__ pidx,
                       unsigned* __restrict__ tlist,
                       int* __restrict__ goff, int* __restrict__ grows,
                       unsigned* __restrict__ table, int* __restrict__ ntiles) {
  __shared__ int sp[N_];
  __shared__ int cnt[L_], pos[L_];
  const int tid = threadIdx.x;          /* 512 threads, one per segment */
  if (tid < N_) sp[tid] = pidx[tid];
  if (tid < L_) cnt[tid] = 0;
  __syncthreads();

  int start = tid ? sp[tid - 1] + 1 : 0;
  int len = sp[tid] - start + 1;
  if (len < 0) len = 0;                  /* duplicate index -> empty segment */
  const int nfull = len < 15 ? len : 15;

  for (int l2 = 0; l2 < nfull; ++l2) atomicAdd(&cnt[l2], 1);
  if (len > 15) atomicAdd(&cnt[15], (len - 15 + 254) / 255);
  if (tid == N_ - 1) {
    int invlen = T_ - 1 - sp[N_ - 1];
    if (invlen > 0) atomicAdd(&cnt[15], (invlen + 254) / 255);
  }
  __syncthreads();
  if (tid == 0) {
    int off = 0;
    for (int l2 = 0; l2 < L_; ++l2) {
      pos[l2] = off; goff[l2] = off; grows[l2] = cnt[l2] * B_;
      off += cnt[l2];
    }
  }
  __syncthreads();

  for (int l2 = 0; l2 < nfull; ++l2) {
    int p = atomicAdd(&pos[l2], 1);
    tlist[p] = (unsigned)(start + l2) | ((unsigned)tid << 12) | (1u << 22);
  }
  if (len > 15) {
    int rem = len - 15, tt2 = start + 15;
    while (rem > 0) {
      int rr = rem > 255 ? 255 : rem;
      int p = atomicAdd(&pos[15], 1);
      tlist[p] = (unsigned)tt2 | ((unsigned)tid << 12) | ((unsigned)rr << 22);
      tt2 += rr; rem -= rr;
    }
  }
  if (tid == N_ - 1) {
    int tt2 = sp[N_ - 1] + 1;
    int rem = T_ - tt2;
    while (rem > 0) {
      int rr = rem > 255 ? 255 : rem;
      int p = atomicAdd(&pos[15], 1);
      tlist[p] = (unsigned)tt2 | (1023u << 12) | ((unsigned)rr << 22);
      tt2 += rr; rem -= rr;
    }
  }
  __syncthreads();
  if (tid == 0) {
    int tt = 0;
    for (int l2 = 0; l2 < L_; ++l2) {
      int rows = cnt[l2] * B_;
      for (int r0 = 0; r0 < rows; r0 += BM) table[tt++] = (unsigned)l2 | ((unsigned)r0 << 4);
    }
    *ntiles = tt;
  }
}

/* ---------------- kernel 3: grouped gather-GEMM (R4 structure) ----------
   256x128 tile, BK=32, 8 waves (4M x 2N), per-wave 64x64 output.
   Triple-buffered LDS (72 KiB -> 2 blocks/CU), depth-2 prefetch, vmcnt(3),
   CORRECTED 4-slot swizzle g(row)=(row>>1)&3 (2-way = free), setprio,
   nt=bid&7 L2 pinning, dedup rep-write epilogue.                           */
__global__ __launch_bounds__(512, 4)
void k_gemm(const unsigned short* __restrict__ wsP,
            const unsigned short* __restrict__ wsW,
            const unsigned* __restrict__ tlist,
            const int* __restrict__ goff,
            const int* __restrict__ grows,
            const unsigned* __restrict__ table,
            const int* __restrict__ ntiles,
            float* __restrict__ out) {
  const int bid = blockIdx.x;
  const int mt = bid >> 3;
  const int nt = bid & 7;            /* nt == XCD: W slice stays in one L2 */
  if (mt >= *ntiles) return;

  const unsigned te = table[mt];
  const int l    = te & 15;
  const int row0 = (int)(te >> 4);
  const int toff = goff[l];
  const int rows = grows[l];

  __shared__ __align__(16) unsigned short As[3][BM * BK];  /* 3 x 16 KiB */
  __shared__ __align__(16) unsigned short Bs[3][BN * BK];  /* 3 x  8 KiB */

  const int tid  = threadIdx.x;
  const int lane = tid & 63;
  const int w    = tid >> 6;      /* 0..7 */
  const int wm   = w >> 1;        /* 0..3 : 64-row band */
  const int wn   = w & 1;         /* 0..1 : 64-col half */

  /* ---- staging source pointers (inverse-swizzled 16B slot on SOURCE) ----
     g(row) = (row>>1)&3 : spreads the 16-lane row-groups 2-way over banks */
  const int srow = tid >> 2;                       /* 0..127 */
  const int sx4  = ((tid & 3) ^ ((srow >> 1) & 3)) * 16;
  const char* aptr0;
  const char* aptr1;
  {
    long re[2];
#pragma unroll
    for (int r = 0; r < 2; ++r) {
      int rg = row0 + r * 128 + srow;
      if (rg < rows) {
        unsigned e = tlist[toff + (rg >> 3)];
        unsigned n = (e >> 12) & 0x3FF;
        int b = rg & 7;
        re[r] = (n >= N_) ? ZROW * (long)DIN
                          : ((long)(b * N_ + (int)n)) * DIN;
      } else re[r] = ZROW * (long)DIN;
    }
    aptr0 = (const char*)(wsP + re[0]) + sx4;
    aptr1 = (const char*)(wsP + re[1]) + sx4;
  }
  const char* bptr = (const char*)(wsW + ((long)l * DOUT + nt * BN + srow) * DIN) + sx4;

/* stage one K-tile: A 256x32 (2 rounds) + B 128x32 (1 round), 3 loads/thread */
#define STG(t_, sb) do { \
  gload_lds16(aptr0 + (t_) * 64, (char*)As[sb] + w * 1024); \
  gload_lds16(aptr1 + (t_) * 64, (char*)As[sb] + 8192 + w * 1024); \
  gload_lds16(bptr  + (t_) * 64, (char*)Bs[sb] + w * 1024); } while (0)

  /* ---- fragment read offsets (same XOR on read side) ---- */
  const int arow = wm * 64 + (lane & 15);          /* LDS row for af[0] */
  const int brow = wn * 64 + (lane & 15);
  const int axr  = ((lane >> 4) ^ (((lane & 15) >> 1) & 3)) * 16;

  f32x4 acc[4][4];
#pragma unroll
  for (int m = 0; m < 4; ++m)
#pragma unroll
    for (int n = 0; n < 4; ++n)
      acc[m][n] = (f32x4){0.f, 0.f, 0.f, 0.f};

  short8 af[4], bf[4];

#define PHASE(t_, bb, sb) do { \
  const int t2_ = (t_) + 2; \
  if (t2_ < NKT) STG(t2_, sb); \
  _Pragma("unroll") for (int m_ = 0; m_ < 4; ++m_) \
    af[m_] = *(const short8*)((const char*)As[bb] + (arow + m_ * 16) * 64 + axr); \
  _Pragma("unroll") for (int n_ = 0; n_ < 4; ++n_) \
    bf[n_] = *(const short8*)((const char*)Bs[bb] + (brow + n_ * 16) * 64 + axr); \
  bar(); \
  asm volatile("s_waitcnt lgkmcnt(0)" ::: "memory"); \
  __builtin_amdgcn_s_setprio(1); \
  _Pragma("unroll") for (int n_ = 0; n_ < 4; ++n_) \
    _Pragma("unroll") for (int m_ = 0; m_ < 4; ++m_) \
      acc[m_][n_] = __builtin_amdgcn_mfma_f32_16x16x32_bf16(af[m_], bf[n_], acc[m_][n_], 0, 0, 0); \
  __builtin_amdgcn_s_setprio(0); \
  if (t2_ < NKT) asm volatile("s_waitcnt vmcnt(3)" ::: "memory"); \
  else           asm volatile("s_waitcnt vmcnt(0)" ::: "memory"); \
  bar(); \
} while (0)

  /* ---- prologue: tiles 0,1 -> bufs 0,1; tile0 complete before phase 0 ---- */
  STG(0, 0);
  STG(1, 1);
  asm volatile("s_waitcnt vmcnt(3)" ::: "memory");
  bar();

  for (int j = 0; j < 11; ++j) {
    const int t0 = 3 * j;
    if (t0     < NKT) PHASE(t0,     0, 2);
    if (t0 + 1 < NKT) PHASE(t0 + 1, 1, 0);
    if (t0 + 2 < NKT) PHASE(t0 + 2, 2, 1);
  }

  /* ---- epilogue: C/D layout col=lane&15, row=(lane>>4)*4+j; rep-write ---- */
#pragma unroll
  for (int m = 0; m < 4; ++m) {
#pragma unroll
    for (int jj = 0; jj < 4; ++jj) {
      int rt = wm * 64 + m * 16 + (lane >> 4) * 4 + jj;
      int rg = row0 + rt;
      if (rg >= rows) continue;
      unsigned e = tlist[toff + (rg >> 3)];
      int b = rg & 7;
      int t0 = (int)(e & 0xFFFu);
      int rep = (int)(e >> 22);
      float* orow = out + ((long)b * T_ + t0) * DOUT + nt * BN + wn * 64 + (lane & 15);
      for (int r = 0; r < rep; ++r) {
#pragma unroll
        for (int n = 0; n < 4; ++n)
          orow[n * 16] = acc[m][n][jj];
        orow += DOUT;
      }
    }
  }
#undef STG
#undef PHASE
}

/* ---------------- launch ---------------- */
extern "C" void kernel_launch(void* const* d_in, const int* in_sizes, int n_in,
                              void* d_out, int out_size, void* d_ws, size_t ws_size,
                              hipStream_t stream) {
  const float* pooled = (const float*)d_in[0];
  const float* W      = (const float*)d_in[1];
  const int*   pidx   = (const int*)d_in[2];
  float* out = (float*)d_out;

  char* ws = (char*)d_ws;
  unsigned short* wsP = (unsigned short*)(ws);
  unsigned short* wsW = (unsigned short*)(ws + WS_W_OFF);
  int* meta  = (int*)(ws + WS_META_OFF);
  unsigned* tlist = (unsigned*)meta;
  int* goff  = meta + 8 * T_;
  int* grows = meta + 8 * T_ + 16;
  unsigned* table = (unsigned*)(meta + 8 * T_ + 32);
  int* ntiles = meta + 8 * T_ + 32 + MT_MAX;

  k_prep<<<1, 512, 0, stream>>>(pidx, tlist, goff, grows, table, ntiles);
  k_convert<<<2048, 256, 0, stream>>>(pooled, W, wsP, wsW);
  k_gemm<<<MT_MAX * NB, 512, 0, stream>>>(wsP, wsW, tlist, goff, grows, table,
                                          ntiles, out);
}